// Round 8
// baseline (332.254 us; speedup 1.0000x reference)
//
#include <hip/hip_runtime.h>
#include <hip/hip_bf16.h>

using u64 = unsigned long long;

constexpr int Bb    = 4;
constexpr int Nn    = 2048;
constexpr int INDIM = 64;
constexpr int HID   = 128;      // HIDDEN == OUT_DIM == 128
constexpr int NW    = Nn / 64;  // mask words per row = 32

// ---------------------------------------------------------------- normalize
__global__ __launch_bounds__(128) void k_norm(const float* __restrict__ emb,
                                              float* __restrict__ ne) {
    const int r = blockIdx.x, c = threadIdx.x;
    const float v = emb[(size_t)r * HID + c];
    __shared__ float red[128];
    red[c] = v * v;
    __syncthreads();
    for (int s = 64; s > 0; s >>= 1) {
        if (c < s) red[c] += red[c + s];
        __syncthreads();
    }
    const float tot = red[0];
    ne[(size_t)r * HID + c] = v * rsqrtf(tot + 1e-12f);
}

// ---------------------------------------- adj Gram + ballot bitmask (naive)
__global__ __launch_bounds__(64) void k_adj(const float* __restrict__ ne,
                                            u64* __restrict__ maskw) {
    const int row  = blockIdx.x >> 5;   // i in [0,2048)
    const int w    = blockIdx.x & 31;   // word in [0,32)
    const int lane = threadIdx.x;       // j = w*64 + lane
    const float* ri = ne + (size_t)row * HID;
    const float* rj = ne + ((size_t)(w << 6) + lane) * HID;
    float acc = 0.f;
    #pragma unroll 8
    for (int k = 0; k < HID; ++k) acc += ri[k] * rj[k];
    const u64 bits = __ballot(acc > 0.5f);
    if (lane == 0) maskw[(size_t)row * NW + w] = bits;
}

// ------------------------------------------- h = x@Wp + bp  (one batch)
__global__ __launch_bounds__(128) void k_proj(const float* __restrict__ x,
                                              const float* __restrict__ Wp,
                                              const float* __restrict__ bp,
                                              float* __restrict__ h) {
    const int row = blockIdx.x;   // n in [0,N)
    const int c   = threadIdx.x;  // 0..127
    __shared__ float xr[INDIM];
    if (c < INDIM) xr[c] = x[(size_t)row * INDIM + c];
    __syncthreads();
    float acc = bp[c];
    #pragma unroll
    for (int k = 0; k < INDIM; ++k)
        acc += xr[k] * Wp[k * HID + c];
    h[(size_t)row * HID + c] = acc;
}

// ---------------- hh = h@W ; s_src/s_dst per-head reductions (one batch)
__global__ __launch_bounds__(128) void k_hidden(const float* __restrict__ hin,
                                                const float* __restrict__ W,
                                                const float* __restrict__ asrc,
                                                const float* __restrict__ adst,
                                                float* __restrict__ hh,
                                                float* __restrict__ ssrc,
                                                float* __restrict__ sdst) {
    const int row = blockIdx.x;   // n
    const int c   = threadIdx.x;  // 0..127, channel; head = c>>5
    __shared__ float hr[HID];
    hr[c] = hin[(size_t)row * HID + c];
    __syncthreads();
    float acc = 0.f;
    #pragma unroll 8
    for (int k = 0; k < HID; ++k)
        acc += hr[k] * W[k * HID + c];
    hh[(size_t)row * HID + c] = acc;

    __shared__ float rs[HID], rd[HID];
    rs[c] = acc * asrc[c];
    rd[c] = acc * adst[c];
    __syncthreads();
    for (int s = 16; s > 0; s >>= 1) {
        if ((c & 31) < s) {
            rs[c] += rs[c + s];
            rd[c] += rd[c + s];
        }
        __syncthreads();
    }
    if ((c & 31) == 0) {
        ssrc[(size_t)row * 4 + (c >> 5)] = rs[c];
        sdst[(size_t)row * 4 + (c >> 5)] = rd[c];
    }
}

// ------------- masked online-softmax aggregation, one batch (bitmask scan)
// FINAL=0: apply exact-erf GELU, write to intermediate buffer.
// FINAL=1: plain write. BOTH write float32 (reference output dtype is f32).
template <int FINAL>
__global__ __launch_bounds__(64) void k_gat(const float* __restrict__ hh,
                                            const float* __restrict__ ssrc,
                                            const float* __restrict__ sdst,
                                            const u64* __restrict__ maskw,
                                            const float* __restrict__ bias,
                                            float* __restrict__ out) {
    const int i    = blockIdx.x;        // node i in [0,N)
    const int lane = threadIdx.x;       // channels: lane (heads 0/1), lane+64 (heads 2/3)
    const int h0   = lane >> 5;
    const int h1   = 2 + h0;
    const float sd0 = sdst[(size_t)i * 4 + h0];
    const float sd1 = sdst[(size_t)i * 4 + h1];
    const u64* mrow = maskw + (size_t)i * NW;

    float m0 = -INFINITY, l0 = 0.f, a0 = 0.f;
    float m1 = -INFINITY, l1 = 0.f, a1 = 0.f;

    for (int w = 0; w < NW; ++w) {
        u64 word = mrow[w];
        while (word) {
            const int bit = __builtin_ctzll(word);
            word &= word - 1;
            const int j = (w << 6) + bit;
            float e0 = sd0 + ssrc[(size_t)j * 4 + h0];
            e0 = e0 > 0.f ? e0 : 0.2f * e0;
            float e1 = sd1 + ssrc[(size_t)j * 4 + h1];
            e1 = e1 > 0.f ? e1 : 0.2f * e1;
            const float v0 = hh[(size_t)j * HID + lane];
            const float v1 = hh[(size_t)j * HID + 64 + lane];
            float nm = fmaxf(m0, e0);
            float sc = __expf(m0 - nm);
            float p  = __expf(e0 - nm);
            l0 = l0 * sc + p; a0 = a0 * sc + p * v0; m0 = nm;
            nm = fmaxf(m1, e1);
            sc = __expf(m1 - nm);
            p  = __expf(e1 - nm);
            l1 = l1 * sc + p; a1 = a1 * sc + p * v1; m1 = nm;
        }
    }

    float o0 = (l0 > 0.f ? a0 / l0 : 0.f) + bias[lane];
    float o1 = (l1 > 0.f ? a1 / l1 : 0.f) + bias[64 + lane];
    if constexpr (!FINAL) {
        o0 = 0.5f * o0 * (1.f + erff(o0 * 0.70710678118654752f));
        o1 = 0.5f * o1 * (1.f + erff(o1 * 0.70710678118654752f));
    }
    out[(size_t)i * HID + lane]      = o0;
    out[(size_t)i * HID + 64 + lane] = o1;
}

// ---------------------------------------------------------------- launcher
extern "C" void kernel_launch(void* const* d_in, const int* in_sizes, int n_in,
                              void* d_out, int out_size, void* d_ws, size_t ws_size,
                              hipStream_t stream) {
    // dict order: x, embedding, Wp, bp, W1, a1_src, a1_dst, b1, W2, a2_src, a2_dst, b2
    const float* x   = (const float*)d_in[0];
    const float* emb = (const float*)d_in[1];
    const float* Wp  = (const float*)d_in[2];
    const float* bp  = (const float*)d_in[3];
    const float* W1  = (const float*)d_in[4];
    const float* a1s = (const float*)d_in[5];
    const float* a1d = (const float*)d_in[6];
    const float* b1  = (const float*)d_in[7];
    const float* W2  = (const float*)d_in[8];
    const float* a2s = (const float*)d_in[9];
    const float* a2d = (const float*)d_in[10];
    const float* b2  = (const float*)d_in[11];

    // Compact workspace: 3.57 MB total (batch processed sequentially).
    char* ws = (char*)d_ws;
    float* ne   = (float*)ws; ws += (size_t)Nn * HID * 4;      // 1 MB
    u64*  maskw = (u64*)ws;   ws += (size_t)Nn * NW * 8;       // 512 KB
    float* hh   = (float*)ws; ws += (size_t)Nn * HID * 4;      // 1 MB (per batch)
    float* buf  = (float*)ws; ws += (size_t)Nn * HID * 4;      // 1 MB (h, then h2)
    float* ssrc = (float*)ws; ws += (size_t)Nn * 4 * 4;        // 32 KB
    float* sdst = (float*)ws; ws += (size_t)Nn * 4 * 4;        // 32 KB

    k_norm<<<Nn, 128, 0, stream>>>(emb, ne);
    k_adj<<<Nn * NW, 64, 0, stream>>>(ne, maskw);

    for (int b = 0; b < Bb; ++b) {
        const float* xb  = x + (size_t)b * Nn * INDIM;
        float*       ob  = (float*)d_out + (size_t)b * Nn * HID;

        k_proj<<<Nn, 128, 0, stream>>>(xb, Wp, bp, buf);
        k_hidden<<<Nn, 128, 0, stream>>>(buf, W1, a1s, a1d, hh, ssrc, sdst);
        k_gat<0><<<Nn, 64, 0, stream>>>(hh, ssrc, sdst, maskw, b1, buf);
        k_hidden<<<Nn, 128, 0, stream>>>(buf, W2, a2s, a2d, hh, ssrc, sdst);
        k_gat<1><<<Nn, 64, 0, stream>>>(hh, ssrc, sdst, maskw, b2, ob);
    }
}

// Round 9
// 79.079 us; speedup vs baseline: 4.2015x; 4.2015x over previous
//
#include <hip/hip_runtime.h>
#include <hip/hip_bf16.h>

using u64 = unsigned long long;

constexpr int Bb    = 4;
constexpr int Nn    = 2048;
constexpr int INDIM = 64;
constexpr int HID   = 128;      // HIDDEN == OUT_DIM == 128
constexpr int NW    = Nn / 64;  // mask words per row = 32

// ---------------------------------------------------------------- normalize
__global__ __launch_bounds__(128) void k_norm(const float* __restrict__ emb,
                                              float* __restrict__ ne) {
    const int r = blockIdx.x, c = threadIdx.x;
    const float v = emb[(size_t)r * HID + c];
    __shared__ float red[128];
    red[c] = v * v;
    __syncthreads();
    for (int s = 64; s > 0; s >>= 1) {
        if (c < s) red[c] += red[c + s];
        __syncthreads();
    }
    const float tot = red[0];
    ne[(size_t)r * HID + c] = v * rsqrtf(tot + 1e-12f);
}

// -------------------- adj Gram: tiled 128x128 register GEMM + bit packing
// grid 16x16 = 256 blocks, 256 threads, 8x8 acc/thread, BK=32 staged in LDS.
__global__ __launch_bounds__(256) void k_adj(const float* __restrict__ ne,
                                             u64* __restrict__ maskw) {
    __shared__ float As[32][132];            // k-major, padded pitch
    __shared__ float Bs[32][132];
    __shared__ unsigned char mb[128][16];    // packed mask bytes
    const int i0 = (blockIdx.x >> 4) * 128;
    const int j0 = (blockIdx.x & 15) * 128;
    const int t  = threadIdx.x;
    const int tx = t & 15, ty = t >> 4;
    const int sr = t >> 1, sh = (t & 1) * 16;   // staging: row, k-half

    float acc[8][8];
    #pragma unroll
    for (int a = 0; a < 8; ++a)
        #pragma unroll
        for (int b = 0; b < 8; ++b) acc[a][b] = 0.f;

    for (int kc = 0; kc < HID; kc += 32) {
        const float* gA = ne + (size_t)(i0 + sr) * HID + kc + sh;
        const float* gB = ne + (size_t)(j0 + sr) * HID + kc + sh;
        #pragma unroll
        for (int e = 0; e < 16; e += 4) {
            const float4 va = *reinterpret_cast<const float4*>(gA + e);
            const float4 vb = *reinterpret_cast<const float4*>(gB + e);
            As[sh + e + 0][sr] = va.x; As[sh + e + 1][sr] = va.y;
            As[sh + e + 2][sr] = va.z; As[sh + e + 3][sr] = va.w;
            Bs[sh + e + 0][sr] = vb.x; Bs[sh + e + 1][sr] = vb.y;
            Bs[sh + e + 2][sr] = vb.z; Bs[sh + e + 3][sr] = vb.w;
        }
        __syncthreads();
        #pragma unroll 4
        for (int k = 0; k < 32; ++k) {
            float a[8], b[8];
            *reinterpret_cast<float4*>(&a[0]) = *reinterpret_cast<const float4*>(&As[k][ty * 8]);
            *reinterpret_cast<float4*>(&a[4]) = *reinterpret_cast<const float4*>(&As[k][ty * 8 + 4]);
            *reinterpret_cast<float4*>(&b[0]) = *reinterpret_cast<const float4*>(&Bs[k][tx * 8]);
            *reinterpret_cast<float4*>(&b[4]) = *reinterpret_cast<const float4*>(&Bs[k][tx * 8 + 4]);
            #pragma unroll
            for (int ii = 0; ii < 8; ++ii)
                #pragma unroll
                for (int jj = 0; jj < 8; ++jj)
                    acc[ii][jj] += a[ii] * b[jj];
        }
        __syncthreads();
    }

    #pragma unroll
    for (int e = 0; e < 8; ++e) {
        unsigned byte = 0;
        #pragma unroll
        for (int jj = 0; jj < 8; ++jj)
            if (acc[e][jj] > 0.5f) byte |= (1u << jj);
        mb[ty * 8 + e][tx] = (unsigned char)byte;
    }
    __syncthreads();
    {
        const int row = t >> 1, w = t & 1;
        const u64 bits = *reinterpret_cast<const u64*>(&mb[row][w * 8]);
        maskw[(size_t)(i0 + row) * NW + (j0 >> 6) + w] = bits;
    }
}

// ------------------- h = x@Wp + bp : 8 rows/block, channel-per-thread
__global__ __launch_bounds__(128) void k_proj(const float* __restrict__ x,
                                              const float* __restrict__ Wp,
                                              const float* __restrict__ bp,
                                              float* __restrict__ h) {
    const int r0 = blockIdx.x * 8;   // flattened b*N row base
    const int c  = threadIdx.x;
    float acc[8];
    const float bias = bp[c];
    #pragma unroll
    for (int r = 0; r < 8; ++r) acc[r] = bias;
    #pragma unroll 4
    for (int k = 0; k < INDIM; ++k) {
        const float wp = Wp[k * HID + c];
        #pragma unroll
        for (int r = 0; r < 8; ++r)
            acc[r] += x[(size_t)(r0 + r) * INDIM + k] * wp;   // block-uniform -> s_load
    }
    #pragma unroll
    for (int r = 0; r < 8; ++r)
        h[(size_t)(r0 + r) * HID + c] = acc[r];
}

// --------- hh = hin@W ; per-head s_src/s_dst : 8 rows/block
__global__ __launch_bounds__(128) void k_hid(const float* __restrict__ hin,
                                             const float* __restrict__ W,
                                             const float* __restrict__ asrc,
                                             const float* __restrict__ adst,
                                             float* __restrict__ hh,
                                             float* __restrict__ ssrc,
                                             float* __restrict__ sdst) {
    const int r0 = blockIdx.x * 8;
    const int c  = threadIdx.x;
    float acc[8];
    #pragma unroll
    for (int r = 0; r < 8; ++r) acc[r] = 0.f;
    #pragma unroll 4
    for (int k = 0; k < HID; ++k) {
        const float w = W[k * HID + c];
        #pragma unroll
        for (int r = 0; r < 8; ++r)
            acc[r] += hin[(size_t)(r0 + r) * HID + k] * w;    // block-uniform -> s_load
    }
    const float as = asrc[c], ad = adst[c];
    #pragma unroll
    for (int r = 0; r < 8; ++r) {
        hh[(size_t)(r0 + r) * HID + c] = acc[r];
        float vs = acc[r] * as;
        float vd = acc[r] * ad;
        #pragma unroll
        for (int m = 1; m < 32; m <<= 1) {   // reduce within 32-lane head groups
            vs += __shfl_xor(vs, m, 32);
            vd += __shfl_xor(vd, m, 32);
        }
        if ((c & 31) == 0) {
            ssrc[(size_t)(r0 + r) * 4 + (c >> 5)] = vs;
            sdst[(size_t)(r0 + r) * 4 + (c >> 5)] = vd;
        }
    }
}

// ------------- masked online-softmax aggregation, batched (bitmask scan)
// FINAL=0: apply exact-erf GELU. Both write float32.
template <int FINAL>
__global__ __launch_bounds__(64) void k_gat(const float* __restrict__ hh,
                                            const float* __restrict__ ssrc,
                                            const float* __restrict__ sdst,
                                            const u64* __restrict__ maskw,
                                            const float* __restrict__ bias,
                                            float* __restrict__ out) {
    const int row  = blockIdx.x;        // b*N + i
    const int i    = row & (Nn - 1);
    const int b    = row >> 11;
    const int lane = threadIdx.x;       // channels: lane (heads 0/1), lane+64 (heads 2/3)
    const int h0   = lane >> 5;
    const int h1   = 2 + h0;
    const float sd0 = sdst[(size_t)row * 4 + h0];
    const float sd1 = sdst[(size_t)row * 4 + h1];
    const u64* mrow = maskw + (size_t)i * NW;

    float m0 = -INFINITY, l0 = 0.f, a0 = 0.f;
    float m1 = -INFINITY, l1 = 0.f, a1 = 0.f;

    for (int w = 0; w < NW; ++w) {
        u64 word = mrow[w];
        while (word) {
            const int bit = __builtin_ctzll(word);
            word &= word - 1;
            const int jr = b * Nn + (w << 6) + bit;
            float e0 = sd0 + ssrc[(size_t)jr * 4 + h0];
            e0 = e0 > 0.f ? e0 : 0.2f * e0;
            float e1 = sd1 + ssrc[(size_t)jr * 4 + h1];
            e1 = e1 > 0.f ? e1 : 0.2f * e1;
            const float v0 = hh[(size_t)jr * HID + lane];
            const float v1 = hh[(size_t)jr * HID + 64 + lane];
            float nm = fmaxf(m0, e0);
            float sc = __expf(m0 - nm);
            float p  = __expf(e0 - nm);
            l0 = l0 * sc + p; a0 = a0 * sc + p * v0; m0 = nm;
            nm = fmaxf(m1, e1);
            sc = __expf(m1 - nm);
            p  = __expf(e1 - nm);
            l1 = l1 * sc + p; a1 = a1 * sc + p * v1; m1 = nm;
        }
    }

    float o0 = (l0 > 0.f ? a0 / l0 : 0.f) + bias[lane];
    float o1 = (l1 > 0.f ? a1 / l1 : 0.f) + bias[64 + lane];
    if constexpr (!FINAL) {
        o0 = 0.5f * o0 * (1.f + erff(o0 * 0.70710678118654752f));
        o1 = 0.5f * o1 * (1.f + erff(o1 * 0.70710678118654752f));
    }
    out[(size_t)row * HID + lane]      = o0;
    out[(size_t)row * HID + 64 + lane] = o1;
}

// ---------------------------------------------------------------- launcher
extern "C" void kernel_launch(void* const* d_in, const int* in_sizes, int n_in,
                              void* d_out, int out_size, void* d_ws, size_t ws_size,
                              hipStream_t stream) {
    // dict order: x, embedding, Wp, bp, W1, a1_src, a1_dst, b1, W2, a2_src, a2_dst, b2
    const float* x   = (const float*)d_in[0];
    const float* emb = (const float*)d_in[1];
    const float* Wp  = (const float*)d_in[2];
    const float* bp  = (const float*)d_in[3];
    const float* W1  = (const float*)d_in[4];
    const float* a1s = (const float*)d_in[5];
    const float* a1d = (const float*)d_in[6];
    const float* b1  = (const float*)d_in[7];
    const float* W2  = (const float*)d_in[8];
    const float* a2s = (const float*)d_in[9];
    const float* a2d = (const float*)d_in[10];
    const float* b2  = (const float*)d_in[11];

    // Workspace: 9.75 MB (rounds 2/3 wrote up to 13.75 MB without anomaly).
    char* ws = (char*)d_ws;
    float* ne   = (float*)ws; ws += (size_t)Nn * HID * 4;          // 1 MB
    u64*  maskw = (u64*)ws;   ws += (size_t)Nn * NW * 8;           // 512 KB
    float* hh   = (float*)ws; ws += (size_t)Bb * Nn * HID * 4;     // 4 MB
    float* buf  = (float*)ws; ws += (size_t)Bb * Nn * HID * 4;     // 4 MB
    float* ssrc = (float*)ws; ws += (size_t)Bb * Nn * 4 * 4;       // 128 KB
    float* sdst = (float*)ws; ws += (size_t)Bb * Nn * 4 * 4;       // 128 KB

    k_norm<<<Nn, 128, 0, stream>>>(emb, ne);
    k_adj<<<256, 256, 0, stream>>>(ne, maskw);

    k_proj<<<Bb * Nn / 8, 128, 0, stream>>>(x, Wp, bp, buf);
    k_hid<<<Bb * Nn / 8, 128, 0, stream>>>(buf, W1, a1s, a1d, hh, ssrc, sdst);
    k_gat<0><<<Bb * Nn, 64, 0, stream>>>(hh, ssrc, sdst, maskw, b1, buf);
    k_hid<<<Bb * Nn / 8, 128, 0, stream>>>(buf, W2, a2s, a2d, hh, ssrc, sdst);
    k_gat<1><<<Bb * Nn, 64, 0, stream>>>(hh, ssrc, sdst, maskw, b2, (float*)d_out);
}